// Round 9
// baseline (125.673 us; speedup 1.0000x reference)
//
#include <hip/hip_runtime.h>
#include <math.h>

constexpr int N = 4096;
constexpr int D = 128;

// ws layout (bytes)
constexpr size_t XBF_OFF = 0;                        // bf16 X image, 4096 x 256 B, XOR-swizzled (1 MB)
constexpr size_t TAB_OFF = (size_t)1 << 20;          // u8 tab[64][4096] = pattern(e1|e2<<1|e3<<2|e0<<3) (256 KB)
constexpr size_t ACC_OFF = TAB_OFF + 64 * 4096;      // float acc5[5][4096] = {U, W, V, P1, P2} (80 KB)
constexpr size_t LSD_OFF = ACC_OFF + 5 * N * 4;      // float lsdiag[4096] (16 KB)
constexpr size_t SUM_OFF = LSD_OFF + N * 4;          // float4 sums[64] = {Sg0, SgB, SgQ, Ce0} (1 KB)

typedef __attribute__((ext_vector_type(8))) short short8;
typedef __attribute__((ext_vector_type(4))) float floatx4;
typedef __attribute__((address_space(1))) unsigned int gu32;
typedef __attribute__((address_space(3))) unsigned int lu32;

__device__ inline unsigned f2bf(float f) {
  unsigned u = __builtin_bit_cast(unsigned, f);
  return (u + 0x7FFFu + ((u >> 16) & 1u)) >> 16;   // RNE
}

// ---- K1: u8 pattern tab + class sums + bf16 image + diag logs + zeroing ----
__global__ __launch_bounds__(256) void k1_prep(
    const float* __restrict__ X, const int* __restrict__ labels,
    char* __restrict__ ws, float* __restrict__ out,
    float B0, float B1, float B2, float B3,
    float Q0, float Q1, float Q2, float Q3) {
  const int b = blockIdx.x, tid = threadIdx.x;
  if (b < 64) {
    const int t = b;
    __shared__ float red[4][4];
    unsigned char* tabu8 = (unsigned char*)(ws + TAB_OFF) + (size_t)t * N;
    float sg0 = 0.f, sgB = 0.f, sgQ = 0.f, ce0 = 0.f;
#pragma unroll 4
    for (int k = 0; k < 16; ++k) {
      const int j = k * 256 + tid;
      const int4 L = ((const int4*)labels)[j];
      const bool e0 = (t == L.x), e1 = (t == L.y), e2 = (t == L.z), e3 = (t == L.w);
      const bool n1 = e3 && !e2, n2 = e2 && !e1, n3 = e1 && !e0;
      sg0 += (e3 ? 0.f : 1.f) + (n1 ? 1.f : 0.f) + (n2 ? 1.f : 0.f) + (n3 ? 1.f : 0.f);
      sgB += (e3 ? 0.f : B0) + (n1 ? B1 : 0.f) + (n2 ? B2 : 0.f) + (n3 ? B3 : 0.f);
      sgQ += (e3 ? 0.f : Q0) + (n1 ? Q1 : 0.f) + (n2 ? Q2 : 0.f) + (n3 ? Q3 : 0.f);
      ce0 += e0 ? 1.f : 0.f;
      tabu8[j] = (unsigned char)((e1 ? 1u : 0u) | (e2 ? 2u : 0u) | (e3 ? 4u : 0u) | (e0 ? 8u : 0u));
    }
    const int w = tid >> 6, lane = tid & 63;
#pragma unroll
    for (int s = 1; s <= 32; s <<= 1) {
      sg0 += __shfl_xor(sg0, s, 64); sgB += __shfl_xor(sgB, s, 64);
      sgQ += __shfl_xor(sgQ, s, 64); ce0 += __shfl_xor(ce0, s, 64);
    }
    if (lane == 0) { red[w][0] = sg0; red[w][1] = sgB; red[w][2] = sgQ; red[w][3] = ce0; }
    __syncthreads();
    if (tid == 0) {
      float* sums = (float*)(ws + SUM_OFF);
      sums[t * 4 + 0] = red[0][0] + red[1][0] + red[2][0] + red[3][0];
      sums[t * 4 + 1] = red[0][1] + red[1][1] + red[2][1] + red[3][1];
      sums[t * 4 + 2] = red[0][2] + red[1][2] + red[2][2] + red[3][2];
      sums[t * 4 + 3] = red[0][3] + red[1][3] + red[2][3] + red[3][3];
    }
  } else if (b < 320) {
    const int task = (b - 64) * 256 + tid;       // 0 .. 65535
    const int r   = task >> 4;
    const int blk = task & 15;
    const float4 x0 = *(const float4*)&X[r * D + blk * 8];
    const float4 x1 = *(const float4*)&X[r * D + blk * 8 + 4];
    uint4 wv;
    wv.x = f2bf(x0.x) | (f2bf(x0.y) << 16);
    wv.y = f2bf(x0.z) | (f2bf(x0.w) << 16);
    wv.z = f2bf(x1.x) | (f2bf(x1.y) << 16);
    wv.w = f2bf(x1.z) | (f2bf(x1.w) << 16);
    *(uint4*)(ws + XBF_OFF + (size_t)r * 256 + ((blk ^ (r & 15)) * 16)) = wv;
  } else if (b < 336) {
    const int i = (b - 320) * 256 + tid;         // 0 .. 4095
    const float* xr = X + i * D;
    float s = 0.f;
#pragma unroll
    for (int c = 0; c < 32; ++c) {
      const float4 v = ((const float4*)xr)[c];
      s += v.x * v.x + v.y * v.y + v.z * v.z + v.w * v.w;
    }
    ((float*)(ws + LSD_OFF))[i] = __logf(s + 1e-6f);
  } else {
    const int idx = (b - 336) * 256 + tid;       // 0 .. 20479 == 5*4096
    ((float*)(ws + ACC_OFF))[idx] = 0.f;
    if (idx == 0) out[0] = 0.f;
  }
}

// ---- phaseA: upper-triangle blocks; one MFMA tile, both direction epilogues ----
__global__ __launch_bounds__(512, 4) void logratio_phaseA(
    const char* __restrict__ ws_ro, const int* __restrict__ labels,
    float* acc5, float B0, float B1, float B2, float B3) {

  // triangular decode: block k -> (bi, bj), bi <= bj
  int k = blockIdx.x;
  int bi = (int)((65.0 - sqrt(4225.0 - 8.0 * (double)k)) * 0.5);
  while (bi > 0 && k < bi * 32 - bi * (bi - 1) / 2) --bi;
  while (k >= (bi + 1) * 32 - (bi + 1) * bi / 2) ++bi;
  const int bj = bi + (k - (bi * 32 - bi * (bi - 1) / 2));
  const int iBase = bi * 128, jBase = bj * 128;
  const bool offdiag = (bi != bj);

  __shared__ __align__(16) char smem[65792];   // [0,32K) B; [32K,64K) A; [64K,+256) pal
                                               // post-MFMA overlay: Red[128][81] at 0, Red2[128][41] at 41472
  const int tid  = threadIdx.x;
  const int w    = tid >> 6;
  const int lane = tid & 63;
  const int lc   = lane & 15;
  const int quad = lane >> 4;

  float4* pal = (float4*)(smem + 65536);
  if (tid < 16) {
    const bool e1 = tid & 1, e2 = tid & 2, e3 = tid & 4, e0 = tid & 8;
    const bool n1 = e3 && !e2, n2 = e2 && !e1, n3 = e1 && !e0;
    const float g0 = (e3 ? 0.f : 1.f) + (n1 ? 1.f : 0.f) + (n2 ? 1.f : 0.f) + (n3 ? 1.f : 0.f);
    const float gB = (e3 ? 0.f : B0) + (n1 ? B1 : 0.f) + (n2 ? B2 : 0.f) + (n3 ? B3 : 0.f);
    pal[tid] = make_float4(gB, g0, e0 ? 1.f : 0.f, 0.f);
  }

  const char* xbf = ws_ro + XBF_OFF;
  const char* gB_ = xbf + (size_t)jBase * 256 + w * 4096 + lane * 16;
  const char* gA_ = xbf + (size_t)iBase * 256 + w * 4096 + lane * 16;
#pragma unroll
  for (int c = 0; c < 4; ++c) {
    __builtin_amdgcn_global_load_lds((const gu32*)(gB_ + c * 1024),
                                     (lu32*)(smem + w * 4096 + c * 1024), 16, 0, 0);
    __builtin_amdgcn_global_load_lds((const gu32*)(gA_ + c * 1024),
                                     (lu32*)(smem + 32768 + w * 4096 + c * 1024), 16, 0, 0);
  }

  // row/col class ids while loads fly
  int tis[4], tcs[8];
#pragma unroll
  for (int reg = 0; reg < 4; ++reg)
    tis[reg] = labels[(iBase + w * 16 + quad * 4 + reg) * 4];
#pragma unroll
  for (int tn = 0; tn < 8; ++tn)
    tcs[tn] = labels[(jBase + tn * 16 + lc) * 4];

  __syncthreads();

  floatx4 acc[8] = {};
  const char* Abase = smem + 32768 + (w * 16 + lc) * 256;
#pragma unroll
  for (int kb = 0; kb < 4; ++kb) {
    const int pb = ((kb * 4 + quad) ^ lc) * 16;
    const short8 af = *(const short8*)(Abase + pb);
    short8 bfr[8];
#pragma unroll
    for (int tn = 0; tn < 8; ++tn)
      bfr[tn] = *(const short8*)(smem + (tn * 16 + lc) * 256 + pb);
#pragma unroll
    for (int tn = 0; tn < 8; ++tn)
      acc[tn] = __builtin_amdgcn_mfma_f32_16x16x32_bf16(af, bfr[tn], acc[tn], 0, 0, 0);
  }

  __syncthreads();              // tile reads done; overlay Red/Red2 (palette stays live)
  float* Red  = (float*)smem;            // [128][81] row partials
  float* Red2 = (float*)(smem + 41472);  // [128][41] col partials (8 w-groups x 5)

  const unsigned char* tabu8 = (const unsigned char*)(ws_ro + TAB_OFF);
  const unsigned char* trow[4];
#pragma unroll
  for (int reg = 0; reg < 4; ++reg)
    trow[reg] = tabu8 + (size_t)tis[reg] * N + jBase + lc;

  float rU[4] = {}, rW[4] = {}, rV[4] = {}, rP1[4] = {}, rP2[4] = {};

#pragma unroll
  for (int tn = 0; tn < 8; ++tn) {
    const unsigned char* tcol = tabu8 + (size_t)tcs[tn] * N + iBase + w * 16 + quad * 4;
    float cU = 0.f, cW = 0.f, cV = 0.f, cP1 = 0.f, cP2 = 0.f;
#pragma unroll
    for (int reg = 0; reg < 4; ++reg) {
      const float ls = __logf(acc[tn][reg] + 1e-6f);
      // row direction (i -> j)
      {
        const float4 pe = pal[trow[reg][tn * 16]];
        const float u = pe.y * ls;
        rU[reg] += u;
        rW[reg] = fmaf(u, ls, rW[reg]);
        rV[reg] = fmaf(pe.x, ls, rV[reg]);
        const float p = pe.z * ls;
        rP1[reg] += p;
        rP2[reg] = fmaf(p, ls, rP2[reg]);
      }
      // col direction (j -> i), only meaningful off-diagonal
      if (offdiag) {
        const float4 pe = pal[tcol[reg]];
        const float u = pe.y * ls;
        cU += u;
        cW = fmaf(u, ls, cW);
        cV = fmaf(pe.x, ls, cV);
        const float p = pe.z * ls;
        cP1 += p;
        cP2 = fmaf(p, ls, cP2);
      }
    }
    if (offdiag) {
      // reduce col partials across the 4 quad groups (same lc)
#pragma unroll
      for (int s = 16; s <= 32; s <<= 1) {
        cU += __shfl_xor(cU, s, 64);  cW += __shfl_xor(cW, s, 64);
        cV += __shfl_xor(cV, s, 64);  cP1 += __shfl_xor(cP1, s, 64);
        cP2 += __shfl_xor(cP2, s, 64);
      }
      if (quad == 0) {
        float* d2 = Red2 + (tn * 16 + lc) * 41 + w * 5;
        d2[0] = cU; d2[1] = cW; d2[2] = cV; d2[3] = cP1; d2[4] = cP2;
      }
    }
  }
#pragma unroll
  for (int reg = 0; reg < 4; ++reg) {
    float* dst = Red + (w * 16 + quad * 4 + reg) * 81 + lc * 5;
    dst[0] = rU[reg]; dst[1] = rW[reg]; dst[2] = rV[reg]; dst[3] = rP1[reg]; dst[4] = rP2[reg];
  }
  __syncthreads();

  if (tid < 128) {
    const int gi = iBase + tid;
    const float* src = Red + tid * 81;
    float s0 = 0.f, s1 = 0.f, s2 = 0.f, s3 = 0.f, s4 = 0.f;
#pragma unroll
    for (int l = 0; l < 16; ++l) {
      s0 += src[l * 5 + 0]; s1 += src[l * 5 + 1]; s2 += src[l * 5 + 2];
      s3 += src[l * 5 + 3]; s4 += src[l * 5 + 4];
    }
    atomicAdd(&acc5[0 * N + gi], s0);
    atomicAdd(&acc5[1 * N + gi], s1);
    atomicAdd(&acc5[2 * N + gi], s2);
    atomicAdd(&acc5[3 * N + gi], s3);
    atomicAdd(&acc5[4 * N + gi], s4);
  } else if (tid < 256 && offdiag) {
    const int col = tid - 128;
    const int gj = jBase + col;
    const float* src = Red2 + col * 41;
    float s0 = 0.f, s1 = 0.f, s2 = 0.f, s3 = 0.f, s4 = 0.f;
#pragma unroll
    for (int l = 0; l < 8; ++l) {
      s0 += src[l * 5 + 0]; s1 += src[l * 5 + 1]; s2 += src[l * 5 + 2];
      s3 += src[l * 5 + 3]; s4 += src[l * 5 + 4];
    }
    atomicAdd(&acc5[0 * N + gj], s0);
    atomicAdd(&acc5[1 * N + gj], s1);
    atomicAdd(&acc5[2 * N + gj], s2);
    atomicAdd(&acc5[3 * N + gj], s3);
    atomicAdd(&acc5[4 * N + gj], s4);
  }
}

// ---- phaseB: fold class constants + diag correction, final reduce ----
__global__ __launch_bounds__(256) void logratio_phaseB(
    const char* __restrict__ ws_ro, const int* __restrict__ labels,
    float* out) {
  const int i = blockIdx.x * 256 + threadIdx.x;
  const float* acc5 = (const float*)(ws_ro + ACC_OFF);
  const float U  = acc5[0 * N + i];
  const float W  = acc5[1 * N + i];
  const float V  = acc5[2 * N + i];
  const float P1 = acc5[3 * N + i];
  const float P2 = acc5[4 * N + i];
  const int t = labels[i * 4];
  const float4 S = ((const float4*)(ws_ro + SUM_OFF))[t];   // {Sg0, SgB, SgQ, Ce0}
  const float lsd = ((const float*)(ws_ro + LSD_OFF))[i];
  const float c  = S.w - 1.f;          // pos diagonal always matches
  const float S1 = P1 - lsd;
  const float S2 = P2 - lsd * lsd;
  const float A  = S.x;
  const float Bv = U + S.y;
  const float Cv = W + 2.f * V + S.z;
  float v = S2 * A - 2.f * S1 * Bv + c * Cv;
#pragma unroll
  for (int m = 32; m >= 1; m >>= 1) v += __shfl_xor(v, m, 64);
  __shared__ float wsum[4];
  if ((threadIdx.x & 63) == 0) wsum[threadIdx.x >> 6] = v;
  __syncthreads();
  if (threadIdx.x == 0) atomicAdd(out, wsum[0] + wsum[1] + wsum[2] + wsum[3]);
}

extern "C" void kernel_launch(void* const* d_in, const int* in_sizes, int n_in,
                              void* d_out, int out_size, void* d_ws, size_t ws_size,
                              hipStream_t stream) {
  const float* inputs = (const float*)d_in[0];
  const int* labels = (const int*)d_in[1];
  float* out = (float*)d_out;
  char* ws = (char*)d_ws;

  float Bq[4], Qq[4];
  for (int m = 0; m < 4; ++m) {
    const float lpv = logf(0.1f + 1e-6f) - logf(powf(0.1f, (float)(5 - m)) + 1e-6f);
    Bq[m] = 0.1f * lpv;
    Qq[m] = Bq[m] * Bq[m];
  }

  k1_prep<<<416, 256, 0, stream>>>(inputs, labels, ws, out,
                                   Bq[0], Bq[1], Bq[2], Bq[3],
                                   Qq[0], Qq[1], Qq[2], Qq[3]);
  logratio_phaseA<<<528, 512, 0, stream>>>(ws, labels, (float*)(ws + ACC_OFF),
                                           Bq[0], Bq[1], Bq[2], Bq[3]);
  logratio_phaseB<<<N / 256, 256, 0, stream>>>(ws, labels, out);
}

// Round 10
// 92.445 us; speedup vs baseline: 1.3594x; 1.3594x over previous
//
#include <hip/hip_runtime.h>
#include <math.h>

constexpr int N = 4096;
constexpr int D = 128;

// ws layout (bytes)
constexpr size_t XBF_OFF = 0;                        // bf16 X image, 4096 x 256 B, XOR-swizzled (1 MB)
constexpr size_t TAB_OFF = (size_t)1 << 20;          // u8 tab[64][4096] = pattern(e1|e2<<1|e3<<2|e0<<3) (256 KB)
constexpr size_t ACC_OFF = TAB_OFF + 64 * 4096;      // float acc5[5][4096] = {U, W, V, P1, P2} (80 KB)
constexpr size_t LSD_OFF = ACC_OFF + 5 * N * 4;      // float lsdiag[4096] (16 KB)
constexpr size_t SUM_OFF = LSD_OFF + N * 4;          // float4 sums[64] = {Sg0, SgB, SgQ, Ce0} (1 KB)

typedef __attribute__((ext_vector_type(8))) short short8;
typedef __attribute__((ext_vector_type(4))) float floatx4;
typedef __attribute__((address_space(1))) unsigned int gu32;
typedef __attribute__((address_space(3))) unsigned int lu32;

__device__ inline unsigned f2bf(float f) {
  unsigned u = __builtin_bit_cast(unsigned, f);
  return (u + 0x7FFFu + ((u >> 16) & 1u)) >> 16;   // RNE
}

// ---- K1: u8 pattern tab + class sums + bf16 image + diag logs + zeroing (unchanged from R8) ----
__global__ __launch_bounds__(256) void k1_prep(
    const float* __restrict__ X, const int* __restrict__ labels,
    char* __restrict__ ws, float* __restrict__ out,
    float B0, float B1, float B2, float B3,
    float Q0, float Q1, float Q2, float Q3) {
  const int b = blockIdx.x, tid = threadIdx.x;
  if (b < 64) {
    const int t = b;
    __shared__ float red[4][4];
    unsigned char* tabu8 = (unsigned char*)(ws + TAB_OFF) + (size_t)t * N;
    float sg0 = 0.f, sgB = 0.f, sgQ = 0.f, ce0 = 0.f;
#pragma unroll 4
    for (int k = 0; k < 16; ++k) {
      const int j = k * 256 + tid;
      const int4 L = ((const int4*)labels)[j];
      const bool e0 = (t == L.x), e1 = (t == L.y), e2 = (t == L.z), e3 = (t == L.w);
      const bool n1 = e3 && !e2, n2 = e2 && !e1, n3 = e1 && !e0;
      sg0 += (e3 ? 0.f : 1.f) + (n1 ? 1.f : 0.f) + (n2 ? 1.f : 0.f) + (n3 ? 1.f : 0.f);
      sgB += (e3 ? 0.f : B0) + (n1 ? B1 : 0.f) + (n2 ? B2 : 0.f) + (n3 ? B3 : 0.f);
      sgQ += (e3 ? 0.f : Q0) + (n1 ? Q1 : 0.f) + (n2 ? Q2 : 0.f) + (n3 ? Q3 : 0.f);
      ce0 += e0 ? 1.f : 0.f;
      tabu8[j] = (unsigned char)((e1 ? 1u : 0u) | (e2 ? 2u : 0u) | (e3 ? 4u : 0u) | (e0 ? 8u : 0u));
    }
    const int w = tid >> 6, lane = tid & 63;
#pragma unroll
    for (int s = 1; s <= 32; s <<= 1) {
      sg0 += __shfl_xor(sg0, s, 64); sgB += __shfl_xor(sgB, s, 64);
      sgQ += __shfl_xor(sgQ, s, 64); ce0 += __shfl_xor(ce0, s, 64);
    }
    if (lane == 0) { red[w][0] = sg0; red[w][1] = sgB; red[w][2] = sgQ; red[w][3] = ce0; }
    __syncthreads();
    if (tid == 0) {
      float* sums = (float*)(ws + SUM_OFF);
      sums[t * 4 + 0] = red[0][0] + red[1][0] + red[2][0] + red[3][0];
      sums[t * 4 + 1] = red[0][1] + red[1][1] + red[2][1] + red[3][1];
      sums[t * 4 + 2] = red[0][2] + red[1][2] + red[2][2] + red[3][2];
      sums[t * 4 + 3] = red[0][3] + red[1][3] + red[2][3] + red[3][3];
    }
  } else if (b < 320) {
    const int task = (b - 64) * 256 + tid;       // 0 .. 65535
    const int r   = task >> 4;
    const int blk = task & 15;
    const float4 x0 = *(const float4*)&X[r * D + blk * 8];
    const float4 x1 = *(const float4*)&X[r * D + blk * 8 + 4];
    uint4 wv;
    wv.x = f2bf(x0.x) | (f2bf(x0.y) << 16);
    wv.y = f2bf(x0.z) | (f2bf(x0.w) << 16);
    wv.z = f2bf(x1.x) | (f2bf(x1.y) << 16);
    wv.w = f2bf(x1.z) | (f2bf(x1.w) << 16);
    *(uint4*)(ws + XBF_OFF + (size_t)r * 256 + ((blk ^ (r & 15)) * 16)) = wv;
  } else if (b < 336) {
    const int i = (b - 320) * 256 + tid;         // 0 .. 4095
    const float* xr = X + i * D;
    float s = 0.f;
#pragma unroll
    for (int c = 0; c < 32; ++c) {
      const float4 v = ((const float4*)xr)[c];
      s += v.x * v.x + v.y * v.y + v.z * v.z + v.w * v.w;
    }
    ((float*)(ws + LSD_OFF))[i] = __logf(s + 1e-6f);
  } else {
    const int idx = (b - 336) * 256 + tid;       // 0 .. 20479 == 5*4096
    ((float*)(ws + ACC_OFF))[idx] = 0.f;
    if (idx == 0) out[0] = 0.f;
  }
}

// ---- phaseA: persistent i-band over 4 j-tiles; R8 inner code; register accumulators ----
__global__ __launch_bounds__(512, 4) void logratio_phaseA(
    const char* __restrict__ ws_ro, const int* __restrict__ labels,
    float* acc5, float B0, float B1, float B2, float B3) {

  __shared__ __align__(16) char smem[65792];   // [0,32K) B; [32K,64K) A; [64K,+256) pal; Red overlays [0,41.5K)

  const int tid  = threadIdx.x;
  const int w    = tid >> 6;     // 8 waves
  const int lane = tid & 63;
  const int lc   = lane & 15;
  const int quad = lane >> 4;
  const int iBase = blockIdx.y * 128;
  const int jt0   = blockIdx.x * 4;            // first of 4 j-tiles

  float4* pal = (float4*)(smem + 65536);
  if (tid < 16) {
    const bool e1 = tid & 1, e2 = tid & 2, e3 = tid & 4, e0 = tid & 8;
    const bool n1 = e3 && !e2, n2 = e2 && !e1, n3 = e1 && !e0;
    const float g0 = (e3 ? 0.f : 1.f) + (n1 ? 1.f : 0.f) + (n2 ? 1.f : 0.f) + (n3 ? 1.f : 0.f);
    const float gB = (e3 ? 0.f : B0) + (n1 ? B1 : 0.f) + (n2 ? B2 : 0.f) + (n3 ? B3 : 0.f);
    pal[tid] = make_float4(gB, g0, e0 ? 1.f : 0.f, 0.f);
  }

  const char* xbf = ws_ro + XBF_OFF;
  // A-tile: staged ONCE per block
  {
    const char* gA_ = xbf + (size_t)iBase * 256 + w * 4096 + lane * 16;
#pragma unroll
    for (int c = 0; c < 4; ++c)
      __builtin_amdgcn_global_load_lds((const gu32*)(gA_ + c * 1024),
                                       (lu32*)(smem + 32768 + w * 4096 + c * 1024), 16, 0, 0);
  }
  // B-tile for q=0
  const char* gBband = xbf + (size_t)jt0 * 128 * 256 + w * 4096 + lane * 16;
#pragma unroll
  for (int c = 0; c < 4; ++c)
    __builtin_amdgcn_global_load_lds((const gu32*)(gBband + c * 1024),
                                     (lu32*)(smem + w * 4096 + c * 1024), 16, 0, 0);

  // row classes + tab row pointers (fixed per block)
  int tis[4];
#pragma unroll
  for (int reg = 0; reg < 4; ++reg)
    tis[reg] = labels[(iBase + w * 16 + quad * 4 + reg) * 4];
  const unsigned char* tabu8 = (const unsigned char*)(ws_ro + TAB_OFF);
  const unsigned char* trow[4];
#pragma unroll
  for (int reg = 0; reg < 4; ++reg)
    trow[reg] = tabu8 + (size_t)tis[reg] * N + lc;

  // persistent per-thread accumulators across the 4 j-tiles
  float rU[4] = {}, rW[4] = {}, rV[4] = {}, rP1[4] = {}, rP2[4] = {};

  const char* Abase = smem + 32768 + (w * 16 + lc) * 256;
#pragma unroll 1
  for (int q = 0; q < 4; ++q) {
    __syncthreads();                 // B(q) staged & visible

    floatx4 acc[8] = {};
#pragma unroll
    for (int kb = 0; kb < 4; ++kb) {
      const int pb = ((kb * 4 + quad) ^ lc) * 16;
      const short8 af = *(const short8*)(Abase + pb);
      short8 bfr[8];
#pragma unroll
      for (int tn = 0; tn < 8; ++tn)
        bfr[tn] = *(const short8*)(smem + (tn * 16 + lc) * 256 + pb);
#pragma unroll
      for (int tn = 0; tn < 8; ++tn)
        acc[tn] = __builtin_amdgcn_mfma_f32_16x16x32_bf16(af, bfr[tn], acc[tn], 0, 0, 0);
    }
    __syncthreads();                 // all B(q) reads done

    // prefetch B(q+1) into the same buffer — overlaps the epilogue below
    if (q < 3) {
      const char* g = gBband + (size_t)(q + 1) * 32768;
#pragma unroll
      for (int c = 0; c < 4; ++c)
        __builtin_amdgcn_global_load_lds((const gu32*)(g + c * 1024),
                                         (lu32*)(smem + w * 4096 + c * 1024), 16, 0, 0);
    }

    // epilogue: registers only (pal is in untouched LDS region)
    const int jBase = (jt0 + q) * 128;
#pragma unroll
    for (int reg = 0; reg < 4; ++reg) {
      const unsigned char* tr = trow[reg] + jBase;
#pragma unroll
      for (int tn = 0; tn < 8; ++tn) {
        const float4 pe = pal[tr[tn * 16]];
        const float ls = __logf(acc[tn][reg] + 1e-6f);
        const float u = pe.y * ls;
        rU[reg] += u;
        rW[reg] = fmaf(u, ls, rW[reg]);
        rV[reg] = fmaf(pe.x, ls, rV[reg]);
        const float p = pe.z * ls;
        rP1[reg] += p;
        rP2[reg] = fmaf(p, ls, rP2[reg]);
      }
    }
  }

  // ---- once per block: Red reduction + atomics (overlays B region; B dead) ----
  float* Red = (float*)smem;         // [128][81]
#pragma unroll
  for (int reg = 0; reg < 4; ++reg) {
    float* dst = Red + (w * 16 + quad * 4 + reg) * 81 + lc * 5;
    dst[0] = rU[reg]; dst[1] = rW[reg]; dst[2] = rV[reg]; dst[3] = rP1[reg]; dst[4] = rP2[reg];
  }
  __syncthreads();

  if (tid < 128) {
    const int gi = iBase + tid;
    const float* src = Red + tid * 81;
    float s0 = 0.f, s1 = 0.f, s2 = 0.f, s3 = 0.f, s4 = 0.f;
#pragma unroll
    for (int l = 0; l < 16; ++l) {
      s0 += src[l * 5 + 0]; s1 += src[l * 5 + 1]; s2 += src[l * 5 + 2];
      s3 += src[l * 5 + 3]; s4 += src[l * 5 + 4];
    }
    atomicAdd(&acc5[0 * N + gi], s0);
    atomicAdd(&acc5[1 * N + gi], s1);
    atomicAdd(&acc5[2 * N + gi], s2);
    atomicAdd(&acc5[3 * N + gi], s3);
    atomicAdd(&acc5[4 * N + gi], s4);
  }
}

// ---- phaseB: fold class constants + diag correction, final reduce (unchanged) ----
__global__ __launch_bounds__(256) void logratio_phaseB(
    const char* __restrict__ ws_ro, const int* __restrict__ labels,
    float* out) {
  const int i = blockIdx.x * 256 + threadIdx.x;
  const float* acc5 = (const float*)(ws_ro + ACC_OFF);
  const float U  = acc5[0 * N + i];
  const float W  = acc5[1 * N + i];
  const float V  = acc5[2 * N + i];
  const float P1 = acc5[3 * N + i];
  const float P2 = acc5[4 * N + i];
  const int t = labels[i * 4];
  const float4 S = ((const float4*)(ws_ro + SUM_OFF))[t];   // {Sg0, SgB, SgQ, Ce0}
  const float lsd = ((const float*)(ws_ro + LSD_OFF))[i];
  const float c  = S.w - 1.f;          // pos diagonal always matches
  const float S1 = P1 - lsd;
  const float S2 = P2 - lsd * lsd;
  const float A  = S.x;
  const float Bv = U + S.y;
  const float Cv = W + 2.f * V + S.z;
  float v = S2 * A - 2.f * S1 * Bv + c * Cv;
#pragma unroll
  for (int m = 32; m >= 1; m >>= 1) v += __shfl_xor(v, m, 64);
  __shared__ float wsum[4];
  if ((threadIdx.x & 63) == 0) wsum[threadIdx.x >> 6] = v;
  __syncthreads();
  if (threadIdx.x == 0) atomicAdd(out, wsum[0] + wsum[1] + wsum[2] + wsum[3]);
}

extern "C" void kernel_launch(void* const* d_in, const int* in_sizes, int n_in,
                              void* d_out, int out_size, void* d_ws, size_t ws_size,
                              hipStream_t stream) {
  const float* inputs = (const float*)d_in[0];
  const int* labels = (const int*)d_in[1];
  float* out = (float*)d_out;
  char* ws = (char*)d_ws;

  float Bq[4], Qq[4];
  for (int m = 0; m < 4; ++m) {
    const float lpv = logf(0.1f + 1e-6f) - logf(powf(0.1f, (float)(5 - m)) + 1e-6f);
    Bq[m] = 0.1f * lpv;
    Qq[m] = Bq[m] * Bq[m];
  }

  k1_prep<<<416, 256, 0, stream>>>(inputs, labels, ws, out,
                                   Bq[0], Bq[1], Bq[2], Bq[3],
                                   Qq[0], Qq[1], Qq[2], Qq[3]);
  dim3 grid(8, 32);   // (j-chunk of 4 tiles, i-band)
  logratio_phaseA<<<grid, 512, 0, stream>>>(ws, labels, (float*)(ws + ACC_OFF),
                                            Bq[0], Bq[1], Bq[2], Bq[3]);
  logratio_phaseB<<<N / 256, 256, 0, stream>>>(ws, labels, out);
}